// Round 6
// baseline (273.211 us; speedup 1.0000x reference)
//
#include <hip/hip_runtime.h>

typedef float f32x4 __attribute__((ext_vector_type(4)));

typedef __attribute__((address_space(1))) const void global_cv;
typedef __attribute__((address_space(3))) void lds_v;

#define N_BINS 15
#define NCLASS 100
#define ROWS   64                 // rows per block-iteration
#define GRID   768                // 3 blocks/CU x 256 CUs

// Barrier-free per-wave async pipeline (R5 minus the lgkmcnt(0)/sched_barrier
// pinning that reproduced the m141 regression):
//   wave w stages f32x4 slots [400w,400w+400) and ONLY its own quads consume
//   them -> no cross-wave LDS dependency -> no __syncthreads in the hot loop.
//   Double-buffered global_load_lds with a single counted wait per iteration:
//   issue stage(t+1)'s 8 loads, then s_waitcnt vmcnt(8) (== stage(t) landed,
//   stage(t+1) still in flight). vmcnt never drains to 0 in the main loop.
//   The compiler keeps full scheduling freedom inside compute (no pinning).
//   Labels ride the same LDS stage so the vmcnt ledger is exactly 8/stage.
__global__ __launch_bounds__(256) void ece_pass1(
    const float* __restrict__ logits,
    const int* __restrict__ labels,
    float* __restrict__ bins,     // ws: [45] accumulators, [45..] counter
    float* __restrict__ out,
    int n_rows, int niter)
{
    __shared__ __align__(16) float stage[2][ROWS * NCLASS];   // 2 x 25600 B
    __shared__ int   lds_lab[2][ROWS];
    __shared__ float priv[45];

    const int tid  = threadIdx.x;
    const int wave = tid >> 6;
    const int lane = tid & 63;
    const int q    = tid & 3;
    const int slot = tid >> 2;                 // row within chunk, 0..63

    if (tid < 45) priv[tid] = 0.f;
    __syncthreads();                           // once, before pipeline starts

    const long max_slot = (long)n_rows * (NCLASS / 4) - 1;
    const f32x4* gv = (const f32x4*)logits;
    const int wbase = wave * 400;              // wave's private f32x4 region

    // stage tile t into buf: 6 full-wave + 1 quarter-wave logits loads +
    // 1 label load = 8 VMEM ops per wave (deterministic vmcnt ledger).
    auto issue_stage = [&](int buf, int t) {
        const long row0 = ((long)t * GRID + blockIdx.x) * ROWS;
        const long s0   = row0 * (NCLASS / 4) + wbase;
        #pragma unroll
        for (int i = 0; i < 6; ++i) {
            long si = s0 + i * 64 + lane;
            si = (si > max_slot) ? max_slot : si;
            __builtin_amdgcn_global_load_lds(
                (global_cv*)(gv + si),
                (lds_v*)&stage[buf][(wbase + i * 64) * 4], 16, 0, 0);
        }
        long si = s0 + 384 + lane;
        si = (si > max_slot) ? max_slot : si;
        long li = row0 + wave * 16 + lane;
        li = (li > n_rows - 1) ? (n_rows - 1) : li;
        if (lane < 16) {                       // exec=0xFFFF -> still 2 VMEM ops
            __builtin_amdgcn_global_load_lds(
                (global_cv*)(gv + si),
                (lds_v*)&stage[buf][(wbase + 384) * 4], 16, 0, 0);
            __builtin_amdgcn_global_load_lds(
                (global_cv*)(labels + li),
                (lds_v*)&lds_lab[buf][wave * 16], 4, 0, 0);
        }
    };

    issue_stage(0, 0);

    for (int t = 0; t < niter; ++t) {
        if (t + 1 < niter) {
            issue_stage((t + 1) & 1, t + 1);
            asm volatile("s_waitcnt vmcnt(8)" ::: "memory");  // stage(t) landed,
        } else {                                              // t+1 still flying
            asm volatile("s_waitcnt vmcnt(0)" ::: "memory");
        }

        const long row = ((long)t * GRID + blockIdx.x) * ROWS + slot;
        const float* rp = &stage[t & 1][slot * NCLASS];
        const f32x4* rv = (const f32x4*)rp;
        const int lab = lds_lab[t & 1][slot];

        // 6 ds_read_b128 per thread (quad covers 64B of the row per i)
        f32x4 F[6];
        #pragma unroll
        for (int i = 0; i < 6; ++i) F[i] = rv[q + 4 * i];

        // tail float4 (96..99): q==0 real, others fmax/exp-neutral sentinel
        f32x4 T = { -1e30f, -1e30f, -1e30f, -1e30f };
        if (q == 0) T = rv[24];

        // 4 independent max chains + 4 independent sum-exp chains
        f32x4 m4 = F[0];
        f32x4 s4;
        s4.x = __expf(F[0].x); s4.y = __expf(F[0].y);
        s4.z = __expf(F[0].z); s4.w = __expf(F[0].w);
        #pragma unroll
        for (int i = 1; i < 6; ++i) {
            m4.x = fmaxf(m4.x, F[i].x); m4.y = fmaxf(m4.y, F[i].y);
            m4.z = fmaxf(m4.z, F[i].z); m4.w = fmaxf(m4.w, F[i].w);
            s4.x += __expf(F[i].x); s4.y += __expf(F[i].y);
            s4.z += __expf(F[i].z); s4.w += __expf(F[i].w);
        }
        m4.x = fmaxf(m4.x, T.x); m4.y = fmaxf(m4.y, T.y);
        m4.z = fmaxf(m4.z, T.z); m4.w = fmaxf(m4.w, T.w);
        s4.x += __expf(T.x); s4.y += __expf(T.y);
        s4.z += __expf(T.z); s4.w += __expf(T.w);

        float vm = fmaxf(fmaxf(m4.x, m4.y), fmaxf(m4.z, m4.w));
        float ss = (s4.x + s4.y) + (s4.z + s4.w);

        // label probe: pred==label <=> logits[row][label]==rowmax
        float pv = 0.f;
        if (q == 0) pv = rp[lab];

        // quad reduction, width 4 -> DPP quad_perm, VALU-speed
        #pragma unroll
        for (int off = 1; off <= 2; off <<= 1) {
            ss += __shfl_xor(ss, off, 4);
            vm = fmaxf(vm, __shfl_xor(vm, off, 4));
        }

        if (q == 0 && row < n_rows) {
            float conf = __expf(vm) / ss;            // = max softmax prob
            int b = (int)ceilf(conf * (float)N_BINS) - 1;
            b = min(max(b, 0), N_BINS - 1);
            atomicAdd(&priv[b],      1.0f);
            atomicAdd(&priv[15 + b], conf);
            atomicAdd(&priv[30 + b], (pv == vm) ? 1.0f : 0.0f);
        }
    }

    __syncthreads();
    if (tid < 45) atomicAdd(&bins[tid], priv[tid]);   // device-scope
    __threadfence();
    __syncthreads();

    // last finished block folds the 15 bins into ECE (fused finalize)
    if (tid == 0) {
        int* ctr = (int*)(bins + 45);
        int old = atomicAdd(ctr, 1);
        if (old == GRID - 1) {
            const float n = (float)n_rows;
            float ece = 0.f;
            #pragma unroll
            for (int i = 0; i < N_BINS; ++i) {
                float cnt = atomicAdd(&bins[i], 0.0f);        // coherent read
                if (cnt > 0.f) {
                    float cs = atomicAdd(&bins[15 + i], 0.0f);
                    float as = atomicAdd(&bins[30 + i], 0.0f);
                    float sc = fmaxf(cnt, 1.0f);
                    ece += fabsf(cs / sc - as / sc) * (cnt / n);
                }
            }
            out[0] = ece;
        }
    }
}

extern "C" void kernel_launch(void* const* d_in, const int* in_sizes, int n_in,
                              void* d_out, int out_size, void* d_ws, size_t ws_size,
                              hipStream_t stream)
{
    const float* logits = (const float*)d_in[0];
    const int*   labels = (const int*)d_in[1];
    float* out  = (float*)d_out;
    float* bins = (float*)d_ws;

    const int n_rows = in_sizes[1];                    // N = 2097152
    const int rows_per_sweep = GRID * ROWS;            // 49152
    const int niter = (n_rows + rows_per_sweep - 1) / rows_per_sweep;  // 43

    hipMemsetAsync(bins, 0, 48 * sizeof(float), stream);  // 45 bins + counter
    ece_pass1<<<GRID, 256, 0, stream>>>(logits, labels, bins, out, n_rows, niter);
}

// Round 7
// 264.740 us; speedup vs baseline: 1.0320x; 1.0320x over previous
//
#include <hip/hip_runtime.h>

typedef float f32x4 __attribute__((ext_vector_type(4)));

typedef __attribute__((address_space(1))) const void global_cv;
typedef __attribute__((address_space(3))) void lds_v;

#define N_BINS 15
#define NCLASS 100
#define ROWS   64                 // rows staged per block-iteration
#define GRID   768                // 3 blocks/CU x 256 CUs (LDS-resident exactly)

// R4 structure (verified 160.9 us) + fused finalize:
//  - global -> LDS via global_load_lds width=16, perfectly linear 16B/lane
//  - barrier-pipelined double buffer: at the barrier, stage(t) has long
//    landed (issued one full iteration earlier), so the compiler's
//    vmcnt(0)-before-s_barrier drain is already satisfied; stage(t+1) is
//    issued right after the barrier and flies under compute(t).
//    (R5/R6's barrier-free counted-vmcnt variant regressed 1.7x: with
//    in-flight LDS-writes at the ds_read point the compiler inserts its own
//    conservative vmcnt(0), serializing the pipeline. Keep the barrier.)
//  - label probe from global (L1/L2-resident line; pred==label <=>
//    logits[row][label]==rowmax, bitwise, since fmaxf returns an input)
//  - fused finalize: last block folds bins -> ECE (one launch removed).
__global__ __launch_bounds__(256) void ece_pass1(
    const float* __restrict__ logits,
    const int* __restrict__ labels,
    float* __restrict__ bins,     // ws: [45] accumulators, [45] counter
    float* __restrict__ out,
    int n_rows, int niter)
{
    __shared__ __align__(16) float stage[2][ROWS * NCLASS];  // 2 x 25600 B
    __shared__ float priv[45];

    const int tid  = threadIdx.x;
    const int wave = tid >> 6;
    const int q    = tid & 3;
    const int slot = tid >> 2;                 // 0..63 -> row within chunk

    if (tid < 45) priv[tid] = 0.f;

    const long max_slot = (long)n_rows * (NCLASS / 4) - 1;
    const f32x4* gv = (const f32x4*)logits;

    // stage one 64-row chunk into stage[buf]; linear 16B/lane, wave-uniform
    // LDS base + lane*16 (global_load_lds requirement).
    auto issue_stage = [&](int buf, long row0) {
        if (row0 >= n_rows) return;
        const long s0 = row0 * (NCLASS / 4);
        #pragma unroll
        for (int r = 0; r < 6; ++r) {          // slots 0..1535
            long si = s0 + r * 256 + tid;
            if (si > max_slot) si = max_slot;  // clamp: junk, never consumed
            __builtin_amdgcn_global_load_lds(
                (global_cv*)(gv + si),
                (lds_v*)&stage[buf][(r * 256 + wave * 64) * 4],
                16, 0, 0);
        }
        if (wave == 0) {                       // slots 1536..1599 (one wave)
            long si = s0 + 1536 + tid;
            if (si > max_slot) si = max_slot;
            __builtin_amdgcn_global_load_lds(
                (global_cv*)(gv + si),
                (lds_v*)&stage[buf][1536 * 4],
                16, 0, 0);
        }
    };

    issue_stage(0, (long)blockIdx.x * ROWS);

    for (int g = 0; g < niter; ++g) {
        // stage(g) landed (issued a full iteration ago) + compute(g-1) done
        __syncthreads();
        if (g + 1 < niter)
            issue_stage((g + 1) & 1,
                        ((long)(g + 1) * gridDim.x + blockIdx.x) * ROWS);

        const long row = ((long)g * gridDim.x + blockIdx.x) * ROWS + slot;
        const float* rp = &stage[g & 1][slot * NCLASS];
        const f32x4* rv = (const f32x4*)rp;

        int lab = 0;
        if (q == 0 && row < n_rows) lab = labels[row];

        // 6 ds_read_b128 per thread (quad covers 64B of the row per i)
        f32x4 F[6];
        #pragma unroll
        for (int i = 0; i < 6; ++i) F[i] = rv[q + 4 * i];

        // tail float4 (elements 96..99): q==0 real, others fmax/exp-neutral
        f32x4 T = { -1e30f, -1e30f, -1e30f, -1e30f };
        if (q == 0) T = rv[24];

        // 4 independent max chains + 4 independent sum-exp chains
        f32x4 m4 = F[0];
        f32x4 s4;
        s4.x = __expf(F[0].x); s4.y = __expf(F[0].y);
        s4.z = __expf(F[0].z); s4.w = __expf(F[0].w);
        #pragma unroll
        for (int i = 1; i < 6; ++i) {
            m4.x = fmaxf(m4.x, F[i].x); m4.y = fmaxf(m4.y, F[i].y);
            m4.z = fmaxf(m4.z, F[i].z); m4.w = fmaxf(m4.w, F[i].w);
            s4.x += __expf(F[i].x); s4.y += __expf(F[i].y);
            s4.z += __expf(F[i].z); s4.w += __expf(F[i].w);
        }
        m4.x = fmaxf(m4.x, T.x); m4.y = fmaxf(m4.y, T.y);
        m4.z = fmaxf(m4.z, T.z); m4.w = fmaxf(m4.w, T.w);
        s4.x += __expf(T.x); s4.y += __expf(T.y);
        s4.z += __expf(T.z); s4.w += __expf(T.w);

        float vm = fmaxf(fmaxf(m4.x, m4.y), fmaxf(m4.z, m4.w));
        float ss = (s4.x + s4.y) + (s4.z + s4.w);

        // label probe from LDS (pred==label <=> logits[row][label]==rowmax)
        float pv = 0.f;
        if (q == 0) pv = rp[lab];

        // quad reduction, width 4 -> DPP quad_perm
        #pragma unroll
        for (int off = 1; off <= 2; off <<= 1) {
            ss += __shfl_xor(ss, off, 4);
            vm = fmaxf(vm, __shfl_xor(vm, off, 4));
        }

        if (q == 0 && row < n_rows) {
            float conf = __expf(vm) / ss;           // = max softmax prob
            int b = (int)ceilf(conf * (float)N_BINS) - 1;
            b = min(max(b, 0), N_BINS - 1);
            atomicAdd(&priv[b],      1.0f);
            atomicAdd(&priv[15 + b], conf);
            atomicAdd(&priv[30 + b], (pv == vm) ? 1.0f : 0.0f);
        }
    }

    __syncthreads();
    if (tid < 45) atomicAdd(&bins[tid], priv[tid]);   // device-scope
    __threadfence();
    __syncthreads();

    // last finished block folds the 15 bins into ECE (fused finalize)
    if (tid == 0) {
        int* ctr = (int*)(bins + 45);
        int old = atomicAdd(ctr, 1);
        if (old == GRID - 1) {
            const float n = (float)n_rows;
            float ece = 0.f;
            #pragma unroll
            for (int i = 0; i < N_BINS; ++i) {
                float cnt = atomicAdd(&bins[i], 0.0f);        // coherent read
                if (cnt > 0.f) {
                    float cs = atomicAdd(&bins[15 + i], 0.0f);
                    float as = atomicAdd(&bins[30 + i], 0.0f);
                    float sc = fmaxf(cnt, 1.0f);
                    ece += fabsf(cs / sc - as / sc) * (cnt / n);
                }
            }
            out[0] = ece;
        }
    }
}

extern "C" void kernel_launch(void* const* d_in, const int* in_sizes, int n_in,
                              void* d_out, int out_size, void* d_ws, size_t ws_size,
                              hipStream_t stream)
{
    const float* logits = (const float*)d_in[0];
    const int*   labels = (const int*)d_in[1];
    float* out  = (float*)d_out;
    float* bins = (float*)d_ws;

    const int n_rows = in_sizes[1];                    // N = 2097152
    const int rows_per_sweep = GRID * ROWS;            // 49152
    const int niter = (n_rows + rows_per_sweep - 1) / rows_per_sweep;  // 43

    hipMemsetAsync(bins, 0, 48 * sizeof(float), stream);  // 45 bins + counter
    ece_pass1<<<GRID, 256, 0, stream>>>(logits, labels, bins, out, n_rows, niter);
}

// Round 8
// 160.618 us; speedup vs baseline: 1.7010x; 1.6483x over previous
//
#include <hip/hip_runtime.h>

typedef float f32x4 __attribute__((ext_vector_type(4)));

typedef __attribute__((address_space(1))) const void global_cv;
typedef __attribute__((address_space(3))) void lds_v;

#define N_BINS 15
#define NCLASS 100
#define ROWS   64                 // rows staged per block-iteration
#define GRID   768                // 3 blocks/CU * 256 CUs (LDS-resident exactly)

// Pass 1 with async linear staging:
//  - global -> LDS via global_load_lds width=16: each block-iteration stages a
//    contiguous, 128B-aligned 25600B chunk (64 rows) with perfectly linear
//    16B/lane requests (identical pattern to the 6.3 TB/s copy ubench).
//  - double-buffered; stage(g+1) issued right after the barrier so HBM stays
//    busy during compute(g) and during the barrier drain.
//  - compute: quad-per-row from LDS (ds_read_b128, baseline bank structure),
//    label probe from LDS (no dependent global load), block bins via LDS
//    atomics (contention hidden under the ~7500-cycle memory period).
__global__ __launch_bounds__(256) void ece_pass1(
    const float* __restrict__ logits,
    const int* __restrict__ labels,
    float* __restrict__ bins,   // [45] global accumulators (zeroed)
    int n_rows, int niter)
{
    __shared__ __align__(16) float stage[2][ROWS * NCLASS];  // 2 x 25600 B
    __shared__ float priv[45];

    const int tid  = threadIdx.x;
    const int wave = tid >> 6;
    const int q    = tid & 3;
    const int slot = tid >> 2;                 // 0..63 -> row within chunk

    if (tid < 45) priv[tid] = 0.f;

    const long max_slot = (long)n_rows * (NCLASS / 4) - 1;
    const f32x4* gv = (const f32x4*)logits;

    // stage one 64-row chunk into stage[buf]; linear 16B/lane, wave-uniform
    // LDS base + lane*16 (global_load_lds requirement).
    auto issue_stage = [&](int buf, long row0) {
        if (row0 >= n_rows) return;
        const long s0 = row0 * (NCLASS / 4);
        #pragma unroll
        for (int r = 0; r < 6; ++r) {          // slots 0..1535
            long si = s0 + r * 256 + tid;
            if (si > max_slot) si = max_slot;  // clamp: junk, never consumed
            __builtin_amdgcn_global_load_lds(
                (global_cv*)(gv + si),
                (lds_v*)&stage[buf][(r * 256 + wave * 64) * 4],
                16, 0, 0);
        }
        if (wave == 0) {                       // slots 1536..1599 (one wave)
            long si = s0 + 1536 + tid;
            if (si > max_slot) si = max_slot;
            __builtin_amdgcn_global_load_lds(
                (global_cv*)(gv + si),
                (lds_v*)&stage[buf][1536 * 4],
                16, 0, 0);
        }
    };

    issue_stage(0, (long)blockIdx.x * ROWS);

    for (int g = 0; g < niter; ++g) {
        // drain (stage g landed for all waves) + compute(g-1) finished
        __syncthreads();
        if (g + 1 < niter)
            issue_stage((g + 1) & 1,
                        ((long)(g + 1) * gridDim.x + blockIdx.x) * ROWS);

        const long row = ((long)g * gridDim.x + blockIdx.x) * ROWS + slot;
        const float* rp = &stage[g & 1][slot * NCLASS];
        const f32x4* rv = (const f32x4*)rp;

        int lab = 0;
        if (q == 0 && row < n_rows) lab = labels[row];

        // 6 ds_read_b128 per thread (quad covers 64B of the row per i)
        f32x4 F[6];
        #pragma unroll
        for (int i = 0; i < 6; ++i) F[i] = rv[q + 4 * i];

        // tail float4 (elements 96..99): q==0 real, others fmax/exp-neutral
        f32x4 T = { -1e30f, -1e30f, -1e30f, -1e30f };
        if (q == 0) T = rv[24];

        // 4 independent max chains + 4 independent sum-exp chains
        f32x4 m4 = F[0];
        f32x4 s4;
        s4.x = __expf(F[0].x); s4.y = __expf(F[0].y);
        s4.z = __expf(F[0].z); s4.w = __expf(F[0].w);
        #pragma unroll
        for (int i = 1; i < 6; ++i) {
            m4.x = fmaxf(m4.x, F[i].x); m4.y = fmaxf(m4.y, F[i].y);
            m4.z = fmaxf(m4.z, F[i].z); m4.w = fmaxf(m4.w, F[i].w);
            s4.x += __expf(F[i].x); s4.y += __expf(F[i].y);
            s4.z += __expf(F[i].z); s4.w += __expf(F[i].w);
        }
        m4.x = fmaxf(m4.x, T.x); m4.y = fmaxf(m4.y, T.y);
        m4.z = fmaxf(m4.z, T.z); m4.w = fmaxf(m4.w, T.w);
        s4.x += __expf(T.x); s4.y += __expf(T.y);
        s4.z += __expf(T.z); s4.w += __expf(T.w);

        float vm = fmaxf(fmaxf(m4.x, m4.y), fmaxf(m4.z, m4.w));
        float ss = (s4.x + s4.y) + (s4.z + s4.w);

        // label probe from LDS (pred==label <=> logits[row][label]==rowmax)
        float pv = 0.f;
        if (q == 0) pv = rp[lab];

        // quad reduction, width 4 -> DPP quad_perm
        #pragma unroll
        for (int off = 1; off <= 2; off <<= 1) {
            ss += __shfl_xor(ss, off, 4);
            vm = fmaxf(vm, __shfl_xor(vm, off, 4));
        }

        if (q == 0 && row < n_rows) {
            float conf = __expf(vm) / ss;           // = max softmax prob
            int b = (int)ceilf(conf * (float)N_BINS) - 1;
            b = min(max(b, 0), N_BINS - 1);
            atomicAdd(&priv[b],      1.0f);
            atomicAdd(&priv[15 + b], conf);
            atomicAdd(&priv[30 + b], (pv == vm) ? 1.0f : 0.0f);
        }
    }

    __syncthreads();
    if (tid < 45) atomicAdd(&bins[tid], priv[tid]);
}

// Pass 2: fold 15 bins into the scalar ECE.
__global__ void ece_final(const float* __restrict__ bins,
                          float* __restrict__ out, float n)
{
    if (threadIdx.x == 0) {
        float ece = 0.f;
        for (int i = 0; i < N_BINS; ++i) {
            float cnt = bins[i];
            if (cnt > 0.f) {
                float sc  = fmaxf(cnt, 1.0f);
                float gap = fabsf(bins[15 + i] / sc - bins[30 + i] / sc);
                ece += gap * (cnt / n);
            }
        }
        out[0] = ece;
    }
}

extern "C" void kernel_launch(void* const* d_in, const int* in_sizes, int n_in,
                              void* d_out, int out_size, void* d_ws, size_t ws_size,
                              hipStream_t stream)
{
    const float* logits = (const float*)d_in[0];
    const int*   labels = (const int*)d_in[1];
    float* out  = (float*)d_out;
    float* bins = (float*)d_ws;

    const int n_rows = in_sizes[1];   // N = 2097152
    const int rows_per_sweep = GRID * ROWS;            // 49152
    const int niter = (n_rows + rows_per_sweep - 1) / rows_per_sweep;  // 43

    hipMemsetAsync(bins, 0, 45 * sizeof(float), stream);
    ece_pass1<<<GRID, 256, 0, stream>>>(logits, labels, bins, n_rows, niter);
    ece_final<<<1, 64, 0, stream>>>(bins, out, (float)n_rows);
}